// Round 7
// baseline (639.527 us; speedup 1.0000x reference)
//
#include <hip/hip_runtime.h>
#include <hip/hip_bf16.h>
#include <math.h>

typedef __bf16 bf16_t;
typedef bf16_t bf16x8 __attribute__((ext_vector_type(8)));
typedef bf16_t bf16x4 __attribute__((ext_vector_type(4)));
typedef float  f32x4  __attribute__((ext_vector_type(4)));

#define HIDDEN 4096
#define NH     32
#define NKV    8
#define HD     128
#define QSZ    4096
#define KVSZ   1024
#define QKVN   6144
#define SEQ    2048
#define ATT_SCALE 0.08838834764831845f   // 1/sqrt(128)
#define KEYMUL 0.5f

// ---- async global->LDS (16B per lane) ----
static __device__ __forceinline__ void gld_lds16(const void* g, void* l) {
  __builtin_amdgcn_global_load_lds((const __attribute__((address_space(1))) char*)g,
                                   (__attribute__((address_space(3))) char*)l, 16, 0, 0);
}

// ---- elementwise fp32 -> bf16 cast ----
__global__ __launch_bounds__(256) void cast_f32_bf16(const float* __restrict__ in,
                                                     bf16_t* __restrict__ out) {
  int i = (blockIdx.x * 256 + threadIdx.x) * 4;
  float4 v = *(const float4*)(in + i);
  bf16x4 o;
  o[0] = (bf16_t)v.x; o[1] = (bf16_t)v.y; o[2] = (bf16_t)v.z; o[3] = (bf16_t)v.w;
  *(bf16x4*)(out + i) = o;
}

// ---- transpose + cast: W[K][N] f32 -> WT[N][K] bf16 ----
__global__ __launch_bounds__(256) void transpose_cast(const float* __restrict__ W,
                                                      bf16_t* __restrict__ WT,
                                                      int K, int N) {
  __shared__ float t[32][33];
  int k0 = blockIdx.y * 32, n0 = blockIdx.x * 32;
  int c = threadIdx.x & 31, r = threadIdx.x >> 5;
#pragma unroll
  for (int rr = r; rr < 32; rr += 8)
    t[rr][c] = W[(size_t)(k0 + rr) * N + n0 + c];
  __syncthreads();
#pragma unroll
  for (int rr = r; rr < 32; rr += 8)
    WT[(size_t)(n0 + rr) * K + k0 + c] = (bf16_t)t[c][rr];
}

// ---- V slice of qkv -> VT[kvh][d][s] bf16 (transposed for PV B-operand) ----
__global__ __launch_bounds__(256) void vprep(const float* __restrict__ qkv,
                                             bf16_t* __restrict__ VT) {
  __shared__ float t[32][33];
  int h = blockIdx.z;
  int s0 = blockIdx.x * 32, d0 = blockIdx.y * 32;
  int c = threadIdx.x & 31, r = threadIdx.x >> 5;
#pragma unroll
  for (int rr = r; rr < 32; rr += 8)
    t[rr][c] = qkv[(size_t)(s0 + rr) * QKVN + QSZ + KVSZ + h * HD + d0 + c];
  __syncthreads();
#pragma unroll
  for (int rr = r; rr < 32; rr += 8)
    VT[((size_t)h * HD + d0 + rr) * SEQ + s0 + c] = (bf16_t)t[c][rr];
}

// ---- RoPE (neox) on q and k, fp32 math, writes head-major bf16 ----
__global__ __launch_bounds__(256) void rope_qk(const float* __restrict__ qkv,
                                               const int* __restrict__ positions,
                                               bf16_t* __restrict__ Qh,
                                               bf16_t* __restrict__ Kh) {
  int s = blockIdx.x;
  float pos = (float)positions[s];
  for (int p = threadIdx.x; p < (NH + NKV) * 64; p += 256) {
    int i = p & 63;
    float inv = powf(100000000000.0f, -(float)i * (1.0f / 64.0f));
    float fr = pos * inv;
    float cs = cosf(fr), sn = sinf(fr);
    if (p < NH * 64) {
      int hh = p >> 6;
      const float* base = qkv + (size_t)s * QKVN + hh * HD;
      float x1 = base[i], x2 = base[i + 64];
      bf16_t* ob = Qh + ((size_t)hh * SEQ + s) * HD;
      ob[i]      = (bf16_t)(x1 * cs - x2 * sn);
      ob[i + 64] = (bf16_t)(x2 * cs + x1 * sn);
    } else {
      int hh = (p - NH * 64) >> 6;
      const float* base = qkv + (size_t)s * QKVN + QSZ + hh * HD;
      float x1 = base[i], x2 = base[i + 64];
      bf16_t* ob = Kh + ((size_t)hh * SEQ + s) * HD;
      ob[i]      = (bf16_t)((x1 * cs - x2 * sn) * KEYMUL);
      ob[i + 64] = (bf16_t)((x2 * cs + x1 * sn) * KEYMUL);
    }
  }
}

// ---- 256x256 8-wave bf16 GEMM, counted-vmcnt double buffer ----
// C[M][N] f32 = A[M][K] * BT[N][K]^T.  512 thr = 8 waves (2M x 4N),
// wave owns 128x64.  BK=64, LDS 2x(32KB A + 32KB B) = 128 KB, 1 block/CU.
// T2: XOR-swizzle byte^=((row&7)<<4) via pre-swizzled global src + swz read.
// T4: raw s_barrier + s_waitcnt vmcnt(8) (never drain-0 in steady state).
// T5: setprio around MFMA clusters.  T1: bijective XCD swizzle (nwg%8==0).
__global__ __launch_bounds__(512, 2) void gemm256(const bf16_t* __restrict__ A,
                                                  const bf16_t* __restrict__ BT,
                                                  float* __restrict__ C,
                                                  int M, int N, int K) {
  __shared__ __align__(16) bf16_t lA[2][256 * 64];
  __shared__ __align__(16) bf16_t lB[2][256 * 64];
  const int tid = threadIdx.x;
  const int w = tid >> 6, lane = tid & 63, l16 = lane & 15, lhi = lane >> 4;
  const int wm2 = w >> 2, wn4 = w & 3;

  const int nbx = N >> 8;
  const int nwg = nbx * (M >> 8);
  int bid = blockIdx.x;
  int swz = (bid & 7) * (nwg >> 3) + (bid >> 3);
  const int bm = swz / nbx, bn = swz % nbx;

  const int NT = K >> 6;

  // staging constants: 4 chunks of 16B per thread per operand tile
  int sRow[4], sCol[4];
#pragma unroll
  for (int i = 0; i < 4; ++i) {
    int X = i * 8192 + tid * 16;
    sRow[i] = X >> 7;                       // 0..255 (tile row, 128B each)
    sCol[i] = (X & 127) ^ ((sRow[i] & 7) << 4);
  }
  const char* Ag = (const char*)(A + (size_t)bm * 256 * K);
  const char* Bg = (const char*)(BT + (size_t)bn * 256 * K);

  auto stage = [&](int t, int buf) {
#pragma unroll
    for (int i = 0; i < 4; ++i)
      gld_lds16(Ag + (size_t)sRow[i] * (K * 2) + t * 128 + sCol[i],
                (char*)&lA[buf][0] + i * 8192 + tid * 16);
#pragma unroll
    for (int i = 0; i < 4; ++i)
      gld_lds16(Bg + (size_t)sRow[i] * (K * 2) + t * 128 + sCol[i],
                (char*)&lB[buf][0] + i * 8192 + tid * 16);
  };

  f32x4 acc[8][4] = {};
  stage(0, 0);
  stage(1, 1);

  for (int t = 0; t < NT; ++t) {
    const int cur = t & 1;
    if (t == NT - 1) asm volatile("s_waitcnt vmcnt(0)" ::: "memory");
    else             asm volatile("s_waitcnt vmcnt(8)" ::: "memory");
    __builtin_amdgcn_s_barrier();
    asm volatile("" ::: "memory");
    const char* Ab = (const char*)&lA[cur][0];
    const char* Bb = (const char*)&lB[cur][0];

    bf16x8 bF[4][2];
#pragma unroll
    for (int n = 0; n < 4; ++n)
#pragma unroll
      for (int ks = 0; ks < 2; ++ks) {
        int row = wn4 * 64 + n * 16 + l16;
        bF[n][ks] = *(const bf16x8*)(Bb + row * 128 + ((ks * 64 + lhi * 16) ^ ((row & 7) << 4)));
      }
#pragma unroll
    for (int q = 0; q < 4; ++q) {
      bf16x8 aF[2][2];
#pragma unroll
      for (int mi = 0; mi < 2; ++mi)
#pragma unroll
        for (int ks = 0; ks < 2; ++ks) {
          int row = wm2 * 128 + (q * 2 + mi) * 16 + l16;
          aF[mi][ks] = *(const bf16x8*)(Ab + row * 128 + ((ks * 64 + lhi * 16) ^ ((row & 7) << 4)));
        }
      __builtin_amdgcn_s_setprio(1);
#pragma unroll
      for (int mi = 0; mi < 2; ++mi)
#pragma unroll
        for (int n = 0; n < 4; ++n)
#pragma unroll
          for (int ks = 0; ks < 2; ++ks)
            acc[q * 2 + mi][n] = __builtin_amdgcn_mfma_f32_16x16x32_bf16(
                aF[mi][ks], bF[n][ks], acc[q * 2 + mi][n], 0, 0, 0);
      __builtin_amdgcn_s_setprio(0);
    }
    asm volatile("" ::: "memory");
    __builtin_amdgcn_s_barrier();
    asm volatile("" ::: "memory");
    if (t + 2 < NT) stage(t + 2, cur);
  }

#pragma unroll
  for (int m = 0; m < 8; ++m) {
    int row = bm * 256 + wm2 * 128 + m * 16 + lhi * 4;
#pragma unroll
    for (int n = 0; n < 4; ++n) {
      int col = bn * 256 + wn4 * 64 + n * 16 + l16;
#pragma unroll
      for (int j = 0; j < 4; ++j)
        C[(size_t)(row + j) * N + col] = acc[m][n][j];
    }
  }
}

// ---- flash-style causal GQA attention (unchanged, verified r4) ----
__global__ __launch_bounds__(256) void attn_kernel(const bf16_t* __restrict__ Q,   // [NH][SEQ][HD]
                                                   const bf16_t* __restrict__ Kb,  // [NKV][SEQ][HD]
                                                   const bf16_t* __restrict__ VT,  // [NKV][HD][SEQ]
                                                   bf16_t* __restrict__ Oa) {      // [SEQ][QSZ]
  __shared__ __align__(16) char KV[2][2][16384];   // [buf][K=0/V=1][16KB]
  __shared__ __align__(16) bf16_t Plds[4][16][72];
  int h = blockIdx.y, p = blockIdx.x;
  int kvh = h >> 2;
  int tid = threadIdx.x;
  int w = tid >> 6, lane = tid & 63;
  int l16 = lane & 15, lhi = lane >> 4;
  int xr = (l16 & 7) << 4;

  int kRow[4], kCol[4], vRow[4], vCol[4], ldsOff[4];
#pragma unroll
  for (int i = 0; i < 4; ++i) {
    int X = w * 4096 + i * 1024 + lane * 16;
    ldsOff[i] = X;
    kRow[i] = X >> 8;
    kCol[i] = (X & 255) ^ ((kRow[i] & 7) << 4);
    vRow[i] = X >> 7;
    vCol[i] = (X & 127) ^ ((vRow[i] & 7) << 4);
  }
  const char* Kg = (const char*)(Kb + (size_t)kvh * SEQ * HD);
  const char* Vg = (const char*)(VT + (size_t)kvh * HD * SEQ);

  int qts[2] = {p, 31 - p};
  int nts[2] = {p + 1, 32 - p};

  for (int ph = 0; ph < 2; ++ph) {
    int qt = qts[ph], ntile = nts[ph];
    int qrow0 = qt * 64 + w * 16;

    bf16x8 qf[4];
    const bf16_t* qbase = Q + ((size_t)h * SEQ + qrow0 + l16) * HD;
#pragma unroll
    for (int kk = 0; kk < 4; ++kk)
      qf[kk] = *(const bf16x8*)(qbase + kk * 32 + lhi * 8);

    f32x4 o[8] = {};
    float m_r[4], l_r[4];
#pragma unroll
    for (int j = 0; j < 4; ++j) { m_r[j] = -1e30f; l_r[j] = 0.0f; }

#pragma unroll
    for (int i = 0; i < 4; ++i) {
      gld_lds16(Kg + (size_t)(0 + kRow[i]) * 256 + kCol[i], &KV[0][0][0] + ldsOff[i]);
      gld_lds16(Vg + (size_t)vRow[i] * (SEQ * 2) + 0 + vCol[i], &KV[0][1][0] + ldsOff[i]);
    }
    __syncthreads();

    for (int kt = 0; kt < ntile; ++kt) {
      int b = kt & 1;
      int kb = kt * 64;
      if (kt + 1 < ntile) {
        int kb2 = kb + 64;
#pragma unroll
        for (int i = 0; i < 4; ++i) {
          gld_lds16(Kg + (size_t)(kb2 + kRow[i]) * 256 + kCol[i], &KV[b ^ 1][0][0] + ldsOff[i]);
          gld_lds16(Vg + (size_t)vRow[i] * (SEQ * 2) + (size_t)kb2 * 2 + vCol[i], &KV[b ^ 1][1][0] + ldsOff[i]);
        }
      }
      const char* Kl = &KV[b][0][0];
      const char* Vl = &KV[b][1][0];

      f32x4 s4[4] = {};
#pragma unroll
      for (int n = 0; n < 4; ++n) {
        int r = n * 16 + l16;
#pragma unroll
        for (int kk = 0; kk < 4; ++kk) {
          bf16x8 kf = *(const bf16x8*)(Kl + r * 256 + ((kk * 64 + lhi * 16) ^ xr));
          s4[n] = __builtin_amdgcn_mfma_f32_16x16x32_bf16(qf[kk], kf, s4[n], 0, 0, 0);
        }
      }
      float pv[4][4];
#pragma unroll
      for (int n = 0; n < 4; ++n) {
        int col = kb + n * 16 + l16;
#pragma unroll
        for (int j = 0; j < 4; ++j) {
          int row = qrow0 + lhi * 4 + j;
          float v = s4[n][j] * ATT_SCALE;
          pv[n][j] = (col > row) ? -1e30f : v;
        }
      }
      float mx[4];
#pragma unroll
      for (int j = 0; j < 4; ++j) {
        mx[j] = fmaxf(fmaxf(pv[0][j], pv[1][j]), fmaxf(pv[2][j], pv[3][j]));
#pragma unroll
        for (int d = 1; d < 16; d <<= 1)
          mx[j] = fmaxf(mx[j], __shfl_xor(mx[j], d));
      }
      float mn[4], sc[4], rs[4];
#pragma unroll
      for (int j = 0; j < 4; ++j) {
        mn[j] = fmaxf(m_r[j], mx[j]);
        sc[j] = __expf(m_r[j] - mn[j]);
        m_r[j] = mn[j];
      }
#pragma unroll
      for (int n = 0; n < 4; ++n)
#pragma unroll
        for (int j = 0; j < 4; ++j)
          pv[n][j] = __expf(pv[n][j] - mn[j]);
#pragma unroll
      for (int j = 0; j < 4; ++j) {
        rs[j] = pv[0][j] + pv[1][j] + pv[2][j] + pv[3][j];
#pragma unroll
        for (int d = 1; d < 16; d <<= 1)
          rs[j] += __shfl_xor(rs[j], d);
        l_r[j] = l_r[j] * sc[j] + rs[j];
      }
#pragma unroll
      for (int nf = 0; nf < 8; ++nf)
#pragma unroll
        for (int j = 0; j < 4; ++j)
          o[nf][j] *= sc[j];
#pragma unroll
      for (int n = 0; n < 4; ++n)
#pragma unroll
        for (int j = 0; j < 4; ++j)
          Plds[w][lhi * 4 + j][n * 16 + l16] = (bf16_t)pv[n][j];
#pragma unroll
      for (int ks = 0; ks < 2; ++ks) {
        bf16x8 pa = *(const bf16x8*)&Plds[w][l16][ks * 32 + lhi * 8];
#pragma unroll
        for (int nf = 0; nf < 8; ++nf) {
          int d = nf * 16 + l16;
          bf16x8 vf = *(const bf16x8*)(Vl + d * 128 + ((ks * 64 + lhi * 16) ^ xr));
          o[nf] = __builtin_amdgcn_mfma_f32_16x16x32_bf16(pa, vf, o[nf], 0, 0, 0);
        }
      }
      __syncthreads();
    }
#pragma unroll
    for (int j = 0; j < 4; ++j) {
      float inv_l = 1.0f / l_r[j];
      int row = qrow0 + lhi * 4 + j;
#pragma unroll
      for (int nf = 0; nf < 8; ++nf)
        Oa[(size_t)row * QSZ + h * HD + nf * 16 + l16] = (bf16_t)(o[nf][j] * inv_l);
    }
    __syncthreads();
  }
}

extern "C" void kernel_launch(void* const* d_in, const int* in_sizes, int n_in,
                              void* d_out, int out_size, void* d_ws, size_t ws_size,
                              hipStream_t stream) {
  const int*   positions = (const int*)d_in[0];
  const float* hidden    = (const float*)d_in[1];
  const float* w_qkv     = (const float*)d_in[2];
  const float* w_o       = (const float*)d_in[3];
  float* out = (float*)d_out;

  char* ws = (char*)d_ws;
  size_t off = 0;
  auto alloc = [&](size_t bytes) { void* p = ws + off; off += (bytes + 255) & ~255ULL; return p; };
  bf16_t* h_bf  = (bf16_t*)alloc((size_t)SEQ * HIDDEN * 2);
  bf16_t* wqkvT = (bf16_t*)alloc((size_t)QKVN * HIDDEN * 2);
  bf16_t* woT   = (bf16_t*)alloc((size_t)HIDDEN * QSZ * 2);
  float*  qkv   = (float*)alloc((size_t)SEQ * QKVN * 4);
  bf16_t* Qh    = (bf16_t*)alloc((size_t)NH * SEQ * HD * 2);
  bf16_t* Kh    = (bf16_t*)alloc((size_t)NKV * SEQ * HD * 2);
  bf16_t* VT    = (bf16_t*)alloc((size_t)NKV * HD * SEQ * 2);
  bf16_t* Oa    = (bf16_t*)alloc((size_t)SEQ * QSZ * 2);
  (void)ws_size; (void)in_sizes; (void)n_in; (void)out_size;

  cast_f32_bf16<<<SEQ * HIDDEN / 4 / 256, 256, 0, stream>>>(hidden, h_bf);
  transpose_cast<<<dim3(QKVN / 32, HIDDEN / 32), 256, 0, stream>>>(w_qkv, wqkvT, HIDDEN, QKVN);
  transpose_cast<<<dim3(HIDDEN / 32, QSZ / 32), 256, 0, stream>>>(w_o, woT, QSZ, HIDDEN);
  gemm256<<<(SEQ / 256) * (QKVN / 256), 512, 0, stream>>>(h_bf, wqkvT, qkv, SEQ, QKVN, HIDDEN);
  rope_qk<<<SEQ, 256, 0, stream>>>(qkv, positions, Qh, Kh);
  vprep<<<dim3(SEQ / 32, HD / 32, NKV), 256, 0, stream>>>(qkv, VT);
  attn_kernel<<<dim3(16, NH), 256, 0, stream>>>(Qh, Kh, VT, Oa);
  gemm256<<<(SEQ / 256) * (HIDDEN / 256), 512, 0, stream>>>(Oa, woT, out, SEQ, HIDDEN, QSZ);
}

// Round 8
// 599.485 us; speedup vs baseline: 1.0668x; 1.0668x over previous
//
#include <hip/hip_runtime.h>
#include <hip/hip_bf16.h>
#include <math.h>

typedef __bf16 bf16_t;
typedef bf16_t bf16x8 __attribute__((ext_vector_type(8)));
typedef bf16_t bf16x4 __attribute__((ext_vector_type(4)));
typedef float  f32x4  __attribute__((ext_vector_type(4)));

#define HIDDEN 4096
#define NH     32
#define NKV    8
#define HD     128
#define QSZ    4096
#define KVSZ   1024
#define QKVN   6144
#define SEQ    2048
#define ATT_SCALE 0.08838834764831845f   // 1/sqrt(128)
#define KEYMUL 0.5f

// ---- async global->LDS (16B per lane) ----
static __device__ __forceinline__ void gld_lds16(const void* g, void* l) {
  __builtin_amdgcn_global_load_lds((const __attribute__((address_space(1))) char*)g,
                                   (__attribute__((address_space(3))) char*)l, 16, 0, 0);
}

// ---- elementwise fp32 -> bf16 cast ----
__global__ __launch_bounds__(256) void cast_f32_bf16(const float* __restrict__ in,
                                                     bf16_t* __restrict__ out) {
  int i = (blockIdx.x * 256 + threadIdx.x) * 4;
  float4 v = *(const float4*)(in + i);
  bf16x4 o;
  o[0] = (bf16_t)v.x; o[1] = (bf16_t)v.y; o[2] = (bf16_t)v.z; o[3] = (bf16_t)v.w;
  *(bf16x4*)(out + i) = o;
}

// ---- transpose + cast: W[K][N] f32 -> WT[N][K] bf16 ----
__global__ __launch_bounds__(256) void transpose_cast(const float* __restrict__ W,
                                                      bf16_t* __restrict__ WT,
                                                      int K, int N) {
  __shared__ float t[32][33];
  int k0 = blockIdx.y * 32, n0 = blockIdx.x * 32;
  int c = threadIdx.x & 31, r = threadIdx.x >> 5;
#pragma unroll
  for (int rr = r; rr < 32; rr += 8)
    t[rr][c] = W[(size_t)(k0 + rr) * N + n0 + c];
  __syncthreads();
#pragma unroll
  for (int rr = r; rr < 32; rr += 8)
    WT[(size_t)(n0 + rr) * K + k0 + c] = (bf16_t)t[c][rr];
}

// ---- V slice of qkv -> VT[kvh][d][s] bf16 ----
__global__ __launch_bounds__(256) void vprep(const float* __restrict__ qkv,
                                             bf16_t* __restrict__ VT) {
  __shared__ float t[32][33];
  int h = blockIdx.z;
  int s0 = blockIdx.x * 32, d0 = blockIdx.y * 32;
  int c = threadIdx.x & 31, r = threadIdx.x >> 5;
#pragma unroll
  for (int rr = r; rr < 32; rr += 8)
    t[rr][c] = qkv[(size_t)(s0 + rr) * QKVN + QSZ + KVSZ + h * HD + d0 + c];
  __syncthreads();
#pragma unroll
  for (int rr = r; rr < 32; rr += 8)
    VT[((size_t)h * HD + d0 + rr) * SEQ + s0 + c] = (bf16_t)t[c][rr];
}

// ---- RoPE (neox) on q and k ----
__global__ __launch_bounds__(256) void rope_qk(const float* __restrict__ qkv,
                                               const int* __restrict__ positions,
                                               bf16_t* __restrict__ Qh,
                                               bf16_t* __restrict__ Kh) {
  int s = blockIdx.x;
  float pos = (float)positions[s];
  for (int p = threadIdx.x; p < (NH + NKV) * 64; p += 256) {
    int i = p & 63;
    float inv = powf(100000000000.0f, -(float)i * (1.0f / 64.0f));
    float fr = pos * inv;
    float cs = cosf(fr), sn = sinf(fr);
    if (p < NH * 64) {
      int hh = p >> 6;
      const float* base = qkv + (size_t)s * QKVN + hh * HD;
      float x1 = base[i], x2 = base[i + 64];
      bf16_t* ob = Qh + ((size_t)hh * SEQ + s) * HD;
      ob[i]      = (bf16_t)(x1 * cs - x2 * sn);
      ob[i + 64] = (bf16_t)(x2 * cs + x1 * sn);
    } else {
      int hh = (p - NH * 64) >> 6;
      const float* base = qkv + (size_t)s * QKVN + QSZ + hh * HD;
      float x1 = base[i], x2 = base[i + 64];
      bf16_t* ob = Kh + ((size_t)hh * SEQ + s) * HD;
      ob[i]      = (bf16_t)((x1 * cs - x2 * sn) * KEYMUL);
      ob[i + 64] = (bf16_t)((x2 * cs + x1 * sn) * KEYMUL);
    }
  }
}

// ---- 256x256 8-wave bf16 GEMM, 8-phase schedule (m201 port) ----
// C[M][N] f32 = A[M][K]*BT[N][K]^T. 512 thr = 8 waves (2M x 4N), wave 128x64.
// BK=64, LDS [2buf][2half][128x64] x (A,B) = 128 KB, 1 block/CU.
// Per K-tile pair: 8 phases {ds_read subtile | stage 1 half | bar | lgkm0 |
// 16 MFMA setprio | bar}; counted vmcnt(4) only at phases 4/8 (0 at tail).
// Half free-map: B halves last-read at nh1 phase, A halves at mh1 phase;
// each stage slot strictly after its region's last read. Ledger verified.
__global__ __launch_bounds__(512, 2) void gemm256(const bf16_t* __restrict__ A,
                                                  const bf16_t* __restrict__ BT,
                                                  float* __restrict__ C,
                                                  int M, int N, int K) {
  __shared__ __align__(16) bf16_t lA[2][2][128 * 64];   // [buf][half][row*64+k]
  __shared__ __align__(16) bf16_t lB[2][2][128 * 64];
  const int tid = threadIdx.x;
  const int w = tid >> 6, lane = tid & 63, l16 = lane & 15, lhi = lane >> 4;
  const int wm2 = w >> 2, wn4 = w & 3;
  const int xr = (l16 & 7) << 4;

  const int nbx = N >> 8;
  const int nwg = nbx * (M >> 8);
  int bid = blockIdx.x;
  int swz = (bid & 7) * (nwg >> 3) + (bid >> 3);
  const int bm = swz / nbx, bn = swz % nbx;

  const int NT = K >> 6;        // K-tiles (64)
  const int NP = NT >> 1;       // pairs

  // staging: 2 chunks of 16B per thread per 16KB half
  int sRow[2], sCol[2];
#pragma unroll
  for (int c = 0; c < 2; ++c) {
    int X = c * 8192 + tid * 16;
    sRow[c] = X >> 7;
    sCol[c] = (X & 127) ^ (((X >> 7) & 7) << 4);
  }
  const char* Ag = (const char*)(A + (size_t)bm * 256 * K);
  const char* Bg = (const char*)(BT + (size_t)bn * 256 * K);

  auto stageA = [&](int t, int buf, int h) {
#pragma unroll
    for (int c = 0; c < 2; ++c)
      gld_lds16(Ag + (size_t)(h * 128 + sRow[c]) * (K * 2) + t * 128 + sCol[c],
                (char*)&lA[buf][h][0] + c * 8192 + tid * 16);
  };
  auto stageB = [&](int t, int buf, int h) {
#pragma unroll
    for (int c = 0; c < 2; ++c)
      gld_lds16(Bg + (size_t)(h * 128 + sRow[c]) * (K * 2) + t * 128 + sCol[c],
                (char*)&lB[buf][h][0] + c * 8192 + tid * 16);
  };

  const char* AbW[2] = {(const char*)&lA[0][wm2][0], (const char*)&lA[1][wm2][0]};
  const char* BbW[2] = {(const char*)&lB[0][wn4 >> 1][0], (const char*)&lB[1][wn4 >> 1][0]};
  const int bRow0 = (wn4 & 1) * 64;

  f32x4 acc[8][4] = {};
  bf16x8 aLo[4][2], aHi[4][2], bLo[2][2], bHi[2][2];

  auto rdA = [&](bf16x8 (&dst)[4][2], int buf, int mh) {
#pragma unroll
    for (int mi = 0; mi < 4; ++mi)
#pragma unroll
      for (int ks = 0; ks < 2; ++ks) {
        int row = (mh * 4 + mi) * 16 + l16;
        dst[mi][ks] = *(const bf16x8*)(AbW[buf] + row * 128 + ((ks * 64 + lhi * 16) ^ xr));
      }
  };
  auto rdB = [&](bf16x8 (&dst)[2][2], int buf, int nh) {
#pragma unroll
    for (int ni = 0; ni < 2; ++ni)
#pragma unroll
      for (int ks = 0; ks < 2; ++ks) {
        int row = bRow0 + (nh * 2 + ni) * 16 + l16;
        dst[ni][ks] = *(const bf16x8*)(BbW[buf] + row * 128 + ((ks * 64 + lhi * 16) ^ xr));
      }
  };
  auto doMFMA = [&](bf16x8 (&a)[4][2], bf16x8 (&b)[2][2], int mh, int nh) {
    __builtin_amdgcn_s_setprio(1);
#pragma unroll
    for (int mi = 0; mi < 4; ++mi)
#pragma unroll
      for (int ni = 0; ni < 2; ++ni)
#pragma unroll
        for (int ks = 0; ks < 2; ++ks)
          acc[mh * 4 + mi][nh * 2 + ni] = __builtin_amdgcn_mfma_f32_16x16x32_bf16(
              a[mi][ks], b[ni][ks], acc[mh * 4 + mi][nh * 2 + ni], 0, 0, 0);
    __builtin_amdgcn_s_setprio(0);
  };
  auto openB = [&]() {
    asm volatile("" ::: "memory");
    __builtin_amdgcn_s_barrier();
    asm volatile("s_waitcnt lgkmcnt(0)" ::: "memory");
    __builtin_amdgcn_sched_barrier(0);
  };
  auto closeB = [&](int vm) {   // vm: -1 none, 4 counted, 0 drain
    asm volatile("" ::: "memory");
    if (vm == 0)      asm volatile("s_waitcnt vmcnt(0)" ::: "memory");
    else if (vm > 0)  asm volatile("s_waitcnt vmcnt(4)" ::: "memory");
    __builtin_amdgcn_s_barrier();
    asm volatile("" ::: "memory");
  };

  // prologue: tile0 full (buf0) + tile1 B halves (buf1); tile1 A staged at P1/P2
  stageA(0, 0, 0); stageA(0, 0, 1); stageB(0, 0, 0); stageB(0, 0, 1);
  if (NT > 1) { stageB(1, 1, 0); stageB(1, 1, 1); }
  asm volatile("s_waitcnt vmcnt(4)" ::: "memory");
  __builtin_amdgcn_s_barrier();
  asm volatile("" ::: "memory");

  for (int ip = 0; ip < NP; ++ip) {
    const int t1 = 2 * ip + 1, t2 = 2 * ip + 2, t3 = 2 * ip + 3;
    const bool s2 = t2 < NT, s3 = t3 < NT;
    // P1: Q0 of buf0
    rdB(bLo, 0, 0); rdA(aLo, 0, 0);
    stageA(t1, 1, 0);
    openB(); doMFMA(aLo, bLo, 0, 0); closeB(-1);
    // P2: Q1
    rdB(bHi, 0, 1);
    stageA(t1, 1, 1);
    openB(); doMFMA(aLo, bHi, 0, 1); closeB(-1);
    // P3: Q2
    rdA(aHi, 0, 1);
    if (s2) stageB(t2, 0, 0);
    openB(); doMFMA(aHi, bLo, 1, 0); closeB(-1);
    // P4: Q3 + tile-boundary vmcnt
    if (s2) stageB(t2, 0, 1);
    openB(); doMFMA(aHi, bHi, 1, 1); closeB(s2 ? 4 : 0);
    // P5: Q0 of buf1
    rdB(bLo, 1, 0); rdA(aLo, 1, 0);
    if (s2) stageA(t2, 0, 0);
    openB(); doMFMA(aLo, bLo, 0, 0); closeB(-1);
    // P6: Q1
    rdB(bHi, 1, 1);
    if (s2) stageA(t2, 0, 1);
    openB(); doMFMA(aLo, bHi, 0, 1); closeB(-1);
    // P7: Q2
    rdA(aHi, 1, 1);
    if (s3) stageB(t3, 1, 0);
    openB(); doMFMA(aHi, bLo, 1, 0); closeB(-1);
    // P8: Q3 + tile-boundary vmcnt
    if (s3) stageB(t3, 1, 1);
    openB(); doMFMA(aHi, bHi, 1, 1); closeB(4);
  }

#pragma unroll
  for (int m = 0; m < 8; ++m) {
    int row = bm * 256 + wm2 * 128 + m * 16 + lhi * 4;
#pragma unroll
    for (int n = 0; n < 4; ++n) {
      int col = bn * 256 + wn4 * 64 + n * 16 + l16;
#pragma unroll
      for (int j = 0; j < 4; ++j)
        C[(size_t)(row + j) * N + col] = acc[m][n][j];
    }
  }
}

// ---- flash-style causal GQA attention (unchanged, verified r4) ----
__global__ __launch_bounds__(256) void attn_kernel(const bf16_t* __restrict__ Q,
                                                   const bf16_t* __restrict__ Kb,
                                                   const bf16_t* __restrict__ VT,
                                                   bf16_t* __restrict__ Oa) {
  __shared__ __align__(16) char KV[2][2][16384];
  __shared__ __align__(16) bf16_t Plds[4][16][72];
  int h = blockIdx.y, p = blockIdx.x;
  int kvh = h >> 2;
  int tid = threadIdx.x;
  int w = tid >> 6, lane = tid & 63;
  int l16 = lane & 15, lhi = lane >> 4;
  int xr = (l16 & 7) << 4;

  int kRow[4], kCol[4], vRow[4], vCol[4], ldsOff[4];
#pragma unroll
  for (int i = 0; i < 4; ++i) {
    int X = w * 4096 + i * 1024 + lane * 16;
    ldsOff[i] = X;
    kRow[i] = X >> 8;
    kCol[i] = (X & 255) ^ ((kRow[i] & 7) << 4);
    vRow[i] = X >> 7;
    vCol[i] = (X & 127) ^ ((vRow[i] & 7) << 4);
  }
  const char* Kg = (const char*)(Kb + (size_t)kvh * SEQ * HD);
  const char* Vg = (const char*)(VT + (size_t)kvh * HD * SEQ);

  int qts[2] = {p, 31 - p};
  int nts[2] = {p + 1, 32 - p};

  for (int ph = 0; ph < 2; ++ph) {
    int qt = qts[ph], ntile = nts[ph];
    int qrow0 = qt * 64 + w * 16;

    bf16x8 qf[4];
    const bf16_t* qbase = Q + ((size_t)h * SEQ + qrow0 + l16) * HD;
#pragma unroll
    for (int kk = 0; kk < 4; ++kk)
      qf[kk] = *(const bf16x8*)(qbase + kk * 32 + lhi * 8);

    f32x4 o[8] = {};
    float m_r[4], l_r[4];
#pragma unroll
    for (int j = 0; j < 4; ++j) { m_r[j] = -1e30f; l_r[j] = 0.0f; }

#pragma unroll
    for (int i = 0; i < 4; ++i) {
      gld_lds16(Kg + (size_t)(0 + kRow[i]) * 256 + kCol[i], &KV[0][0][0] + ldsOff[i]);
      gld_lds16(Vg + (size_t)vRow[i] * (SEQ * 2) + 0 + vCol[i], &KV[0][1][0] + ldsOff[i]);
    }
    __syncthreads();

    for (int kt = 0; kt < ntile; ++kt) {
      int b = kt & 1;
      int kb = kt * 64;
      if (kt + 1 < ntile) {
        int kb2 = kb + 64;
#pragma unroll
        for (int i = 0; i < 4; ++i) {
          gld_lds16(Kg + (size_t)(kb2 + kRow[i]) * 256 + kCol[i], &KV[b ^ 1][0][0] + ldsOff[i]);
          gld_lds16(Vg + (size_t)vRow[i] * (SEQ * 2) + (size_t)kb2 * 2 + vCol[i], &KV[b ^ 1][1][0] + ldsOff[i]);
        }
      }
      const char* Kl = &KV[b][0][0];
      const char* Vl = &KV[b][1][0];

      f32x4 s4[4] = {};
#pragma unroll
      for (int n = 0; n < 4; ++n) {
        int r = n * 16 + l16;
#pragma unroll
        for (int kk = 0; kk < 4; ++kk) {
          bf16x8 kf = *(const bf16x8*)(Kl + r * 256 + ((kk * 64 + lhi * 16) ^ xr));
          s4[n] = __builtin_amdgcn_mfma_f32_16x16x32_bf16(qf[kk], kf, s4[n], 0, 0, 0);
        }
      }
      float pv[4][4];
#pragma unroll
      for (int n = 0; n < 4; ++n) {
        int col = kb + n * 16 + l16;
#pragma unroll
        for (int j = 0; j < 4; ++j) {
          int row = qrow0 + lhi * 4 + j;
          float v = s4[n][j] * ATT_SCALE;
          pv[n][j] = (col > row) ? -1e30f : v;
        }
      }
      float mx[4];
#pragma unroll
      for (int j = 0; j < 4; ++j) {
        mx[j] = fmaxf(fmaxf(pv[0][j], pv[1][j]), fmaxf(pv[2][j], pv[3][j]));
#pragma unroll
        for (int d = 1; d < 16; d <<= 1)
          mx[j] = fmaxf(mx[j], __shfl_xor(mx[j], d));
      }
      float mn[4], sc[4], rs[4];
#pragma unroll
      for (int j = 0; j < 4; ++j) {
        mn[j] = fmaxf(m_r[j], mx[j]);
        sc[j] = __expf(m_r[j] - mn[j]);
        m_r[j] = mn[j];
      }
#pragma unroll
      for (int n = 0; n < 4; ++n)
#pragma unroll
        for (int j = 0; j < 4; ++j)
          pv[n][j] = __expf(pv[n][j] - mn[j]);
#pragma unroll
      for (int j = 0; j < 4; ++j) {
        rs[j] = pv[0][j] + pv[1][j] + pv[2][j] + pv[3][j];
#pragma unroll
        for (int d = 1; d < 16; d <<= 1)
          rs[j] += __shfl_xor(rs[j], d);
        l_r[j] = l_r[j] * sc[j] + rs[j];
      }
#pragma unroll
      for (int nf = 0; nf < 8; ++nf)
#pragma unroll
        for (int j = 0; j < 4; ++j)
          o[nf][j] *= sc[j];
#pragma unroll
      for (int n = 0; n < 4; ++n)
#pragma unroll
        for (int j = 0; j < 4; ++j)
          Plds[w][lhi * 4 + j][n * 16 + l16] = (bf16_t)pv[n][j];
#pragma unroll
      for (int ks = 0; ks < 2; ++ks) {
        bf16x8 pa = *(const bf16x8*)&Plds[w][l16][ks * 32 + lhi * 8];
#pragma unroll
        for (int nf = 0; nf < 8; ++nf) {
          int d = nf * 16 + l16;
          bf16x8 vf = *(const bf16x8*)(Vl + d * 128 + ((ks * 64 + lhi * 16) ^ xr));
          o[nf] = __builtin_amdgcn_mfma_f32_16x16x32_bf16(pa, vf, o[nf], 0, 0, 0);
        }
      }
      __syncthreads();
    }
#pragma unroll
    for (int j = 0; j < 4; ++j) {
      float inv_l = 1.0f / l_r[j];
      int row = qrow0 + lhi * 4 + j;
#pragma unroll
      for (int nf = 0; nf < 8; ++nf)
        Oa[(size_t)row * QSZ + h * HD + nf * 16 + l16] = (bf16_t)(o[nf][j] * inv_l);
    }
    __syncthreads();
  }
}

extern "C" void kernel_launch(void* const* d_in, const int* in_sizes, int n_in,
                              void* d_out, int out_size, void* d_ws, size_t ws_size,
                              hipStream_t stream) {
  const int*   positions = (const int*)d_in[0];
  const float* hidden    = (const float*)d_in[1];
  const float* w_qkv     = (const float*)d_in[2];
  const float* w_o       = (const float*)d_in[3];
  float* out = (float*)d_out;

  char* ws = (char*)d_ws;
  size_t off = 0;
  auto alloc = [&](size_t bytes) { void* p = ws + off; off += (bytes + 255) & ~255ULL; return p; };
  bf16_t* h_bf  = (bf16_t*)alloc((size_t)SEQ * HIDDEN * 2);
  bf16_t* wqkvT = (bf16_t*)alloc((size_t)QKVN * HIDDEN * 2);
  bf16_t* woT   = (bf16_t*)alloc((size_t)HIDDEN * QSZ * 2);
  float*  qkv   = (float*)alloc((size_t)SEQ * QKVN * 4);
  bf16_t* Qh    = (bf16_t*)alloc((size_t)NH * SEQ * HD * 2);
  bf16_t* Kh    = (bf16_t*)alloc((size_t)NKV * SEQ * HD * 2);
  bf16_t* VT    = (bf16_t*)alloc((size_t)NKV * HD * SEQ * 2);
  bf16_t* Oa    = (bf16_t*)alloc((size_t)SEQ * QSZ * 2);
  (void)ws_size; (void)in_sizes; (void)n_in; (void)out_size;

  cast_f32_bf16<<<SEQ * HIDDEN / 4 / 256, 256, 0, stream>>>(hidden, h_bf);
  transpose_cast<<<dim3(QKVN / 32, HIDDEN / 32), 256, 0, stream>>>(w_qkv, wqkvT, HIDDEN, QKVN);
  transpose_cast<<<dim3(HIDDEN / 32, QSZ / 32), 256, 0, stream>>>(w_o, woT, QSZ, HIDDEN);
  gemm256<<<(SEQ / 256) * (QKVN / 256), 512, 0, stream>>>(h_bf, wqkvT, qkv, SEQ, QKVN, HIDDEN);
  rope_qk<<<SEQ, 256, 0, stream>>>(qkv, positions, Qh, Kh);
  vprep<<<dim3(SEQ / 32, HD / 32, NKV), 256, 0, stream>>>(qkv, VT);
  attn_kernel<<<dim3(16, NH), 256, 0, stream>>>(Qh, Kh, VT, Oa);
  gemm256<<<(SEQ / 256) * (HIDDEN / 256), 512, 0, stream>>>(Oa, woT, out, SEQ, HIDDEN, QSZ);
}